// Round 1
// baseline (408.784 us; speedup 1.0000x reference)
//
#include <hip/hip_runtime.h>
#include <type_traits>

typedef __bf16 bf16;
typedef __attribute__((ext_vector_type(8))) __bf16 bf16x8;
typedef __attribute__((ext_vector_type(4))) float f32x4;

constexpr int Bc = 4, Tc = 2048, Cc = 1024, Hc = 16;
constexpr int Mrows = Bc * Tc;   // 8192
constexpr int N3 = 3 * Cc;       // 3072

#define GLOAD(gp, lp)                                                          \
  __builtin_amdgcn_global_load_lds(                                           \
      (const __attribute__((address_space(1))) void*)(gp),                     \
      (__attribute__((address_space(3))) void*)(lp), 16, 0, 0)

// ---------------- cast fp32 -> bf16, 8 elems/thread ----------------
__global__ __launch_bounds__(256) void cast_bf16_kernel(
    const float* __restrict__ in, bf16* __restrict__ out, int n8) {
  int i = blockIdx.x * blockDim.x + threadIdx.x;
  int stride = gridDim.x * blockDim.x;
  for (; i < n8; i += stride) {
    const float4* p = (const float4*)(in + (long)i * 8);
    float4 a = p[0], b = p[1];
    bf16x8 v;
    v[0] = (bf16)a.x; v[1] = (bf16)a.y; v[2] = (bf16)a.z; v[3] = (bf16)a.w;
    v[4] = (bf16)b.x; v[5] = (bf16)b.y; v[6] = (bf16)b.z; v[7] = (bf16)b.w;
    *(bf16x8*)(out + (long)i * 8) = v;
  }
}

// ---------------- transpose + cast: in[rows][cols] f32 -> out[cols][rows] bf16
__global__ __launch_bounds__(256) void transpose_cast_kernel(
    const float* __restrict__ in, bf16* __restrict__ out, int rows, int cols) {
  __shared__ float tile[32][33];
  int tx = threadIdx.x, ty = threadIdx.y;
  int r0 = blockIdx.y * 32, c0 = blockIdx.x * 32;
#pragma unroll
  for (int i = 0; i < 4; i++)
    tile[ty + 8 * i][tx] = in[(long)(r0 + ty + 8 * i) * cols + c0 + tx];
  __syncthreads();
#pragma unroll
  for (int i = 0; i < 4; i++)
    out[(long)(c0 + ty + 8 * i) * rows + r0 + tx] = (bf16)tile[tx][ty + 8 * i];
}

// ---------------- transpose V part of QKV: Y[.,2048+h*64+d] -> Vt[bh][d][t]
__global__ __launch_bounds__(256) void transpose_v_kernel(
    const bf16* __restrict__ Y, bf16* __restrict__ Vt) {
  __shared__ bf16 tile[32][33];
  int tx = threadIdx.x, ty = threadIdx.y;
  int t0 = blockIdx.x * 32;
  int d0 = blockIdx.y * 32;
  int bh = blockIdx.z;
  int b = bh >> 4, h = bh & 15;
  const bf16* src = Y + (long)(b * Tc) * N3 + 2 * Cc + h * 64;
#pragma unroll
  for (int i = 0; i < 4; i++)
    tile[ty + 8 * i][tx] = src[(long)(t0 + ty + 8 * i) * N3 + d0 + tx];
  __syncthreads();
  bf16* dst = Vt + (long)bh * 64 * Tc;
#pragma unroll
  for (int i = 0; i < 4; i++)
    dst[(long)(d0 + ty + 8 * i) * Tc + t0 + tx] = tile[tx][ty + 8 * i];
}

// ---------------- GEMM: C[M,N] = A[M,K](bf16) * Bt[N,K]^T + bias, m97 structure
template <typename OutT>
__global__ __launch_bounds__(256) void gemm_bt_kernel(
    const bf16* __restrict__ A, const bf16* __restrict__ Bt,
    const float* __restrict__ bias, OutT* __restrict__ Cout, int M, int N,
    int K) {
  __shared__ __align__(16) bf16 Alds[128 * 32];
  __shared__ __align__(16) bf16 Blds[128 * 32];
  const int tid = threadIdx.x;
  const int w = tid >> 6, l = tid & 63;
  const int m0 = blockIdx.x * 128, n0 = blockIdx.y * 128;
  const int wr = w >> 1, wc = w & 1;
  f32x4 acc[4][4] = {};
  const int arow = tid >> 2, achunk = tid & 3;
  const bf16* Ag = A + (long)(m0 + arow) * K + achunk * 8;
  const bf16* Bg = Bt + (long)(n0 + arow) * K + achunk * 8;
  char* AldsB = (char*)Alds;
  char* BldsB = (char*)Blds;
  const int wbase = w * 1024;  // wave-uniform LDS byte base

  for (int k0 = 0; k0 < K; k0 += 32) {
    __syncthreads();
    GLOAD(Ag + k0, AldsB + wbase);
    GLOAD(Ag + k0 + (long)64 * K, AldsB + wbase + 4096);
    GLOAD(Bg + k0, BldsB + wbase);
    GLOAD(Bg + k0 + (long)64 * K, BldsB + wbase + 4096);
    __syncthreads();
    const int kk = (l >> 4) * 8;
    bf16x8 af[4], bfr[4];
#pragma unroll
    for (int mi = 0; mi < 4; mi++)
      af[mi] = *(const bf16x8*)(AldsB +
                                ((wr * 64 + mi * 16 + (l & 15)) * 32 + kk) * 2);
#pragma unroll
    for (int ni = 0; ni < 4; ni++)
      bfr[ni] = *(const bf16x8*)(BldsB +
                                 ((wc * 64 + ni * 16 + (l & 15)) * 32 + kk) * 2);
#pragma unroll
    for (int mi = 0; mi < 4; mi++)
#pragma unroll
      for (int ni = 0; ni < 4; ni++)
        acc[mi][ni] = __builtin_amdgcn_mfma_f32_16x16x32_bf16(
            af[mi], bfr[ni], acc[mi][ni], 0, 0, 0);
  }
  const int rrow = (l >> 4) * 4, col = l & 15;
#pragma unroll
  for (int mi = 0; mi < 4; mi++) {
#pragma unroll
    for (int ni = 0; ni < 4; ni++) {
      int gcol = n0 + wc * 64 + ni * 16 + col;
      float bv = bias[gcol];
#pragma unroll
      for (int i = 0; i < 4; i++) {
        int grow = m0 + wr * 64 + mi * 16 + rrow + i;
        float v = acc[mi][ni][i] + bv;
        if constexpr (std::is_same<OutT, float>::value)
          Cout[(long)grow * N + gcol] = v;
        else
          Cout[(long)grow * N + gcol] = (bf16)v;
      }
    }
  }
}

// ---------------- causal flash attention ----------------
// grid (T/64, B*H), 256 thr. Wave w owns q rows [q0+16w, q0+16w+16).
__global__ __launch_bounds__(256) void flash_kernel(
    const bf16* __restrict__ Y, const bf16* __restrict__ Vt,
    bf16* __restrict__ O) {
  __shared__ __align__(16) bf16 Klds[64 * 64];   // [krow][d], chunk-swizzled
  __shared__ __align__(16) bf16 Vlds[64 * 64];   // [d][kk], chunk-swizzled
  __shared__ __align__(16) bf16 Plds[4][16][72];  // per-wave, padded
  const int tid = threadIdx.x;
  const int w = tid >> 6, l = tid & 63;
  const int q0 = blockIdx.x * 64;
  const int bh = blockIdx.y;
  const int b = bh >> 4, h = bh & 15;
  const bf16* Qbase = Y + (long)(b * Tc + q0) * N3 + h * 64;
  const bf16* Kbase = Y + (long)(b * Tc) * N3 + Cc + h * 64;
  const bf16* Vbase = Vt + (long)bh * 64 * Tc;

  bf16x8 aq[2];
  {
    const bf16* qp = Qbase + (long)(w * 16 + (l & 15)) * N3 + ((l >> 4) * 8);
    aq[0] = *(const bf16x8*)(qp);
    aq[1] = *(const bf16x8*)(qp + 32);
  }
  f32x4 o[4] = {};
  float mrun[4], lrun[4];
#pragma unroll
  for (int i = 0; i < 4; i++) {
    mrun[i] = -__builtin_inff();
    lrun[i] = 0.f;
  }

  const int srow = tid >> 3, schunk = tid & 7;
  const int wbase = w * 1024;
  char* KldsB = (char*)Klds;
  char* VldsB = (char*)Vlds;
  const int nkt = blockIdx.x + 1;

  for (int kt = 0; kt < nkt; kt++) {
    const int kt0 = kt * 64;
    __syncthreads();
    {
      int r2 = srow + 32;
      GLOAD(Kbase + (long)(kt0 + srow) * N3 + (schunk ^ (srow & 7)) * 8,
            KldsB + wbase);
      GLOAD(Kbase + (long)(kt0 + r2) * N3 + (schunk ^ (r2 & 7)) * 8,
            KldsB + wbase + 4096);
      GLOAD(Vbase + (long)srow * Tc + kt0 + (schunk ^ (srow & 7)) * 8,
            VldsB + wbase);
      GLOAD(Vbase + (long)r2 * Tc + kt0 + (schunk ^ (r2 & 7)) * 8,
            VldsB + wbase + 4096);
    }
    __syncthreads();

    // S = Q K^T
    f32x4 s[4];
#pragma unroll
    for (int cb = 0; cb < 4; cb++) {
      f32x4 acc = {};
      const int kr = cb * 16 + (l & 15);
#pragma unroll
      for (int dc = 0; dc < 2; dc++) {
        int c = dc * 4 + (l >> 4);
        bf16x8 bk = *(const bf16x8*)(KldsB + kr * 128 + ((c ^ (kr & 7)) * 16));
        acc = __builtin_amdgcn_mfma_f32_16x16x32_bf16(aq[dc], bk, acc, 0, 0, 0);
      }
      s[cb] = acc;
    }
    const bool last = (kt == nkt - 1);
#pragma unroll
    for (int cb = 0; cb < 4; cb++) {
#pragma unroll
      for (int i = 0; i < 4; i++) {
        float v = s[cb][i] * 0.125f;
        if (last) {
          int qrow = q0 + w * 16 + (l >> 4) * 4 + i;
          int kcol = kt0 + cb * 16 + (l & 15);
          if (kcol > qrow) v = -__builtin_inff();
        }
        s[cb][i] = v;
      }
    }
    // online softmax (row stats across the 16-lane col group)
    float p[4][4];
#pragma unroll
    for (int i = 0; i < 4; i++) {
      float pm = fmaxf(fmaxf(s[0][i], s[1][i]), fmaxf(s[2][i], s[3][i]));
#pragma unroll
      for (int msk = 1; msk < 16; msk <<= 1) pm = fmaxf(pm, __shfl_xor(pm, msk));
      float mnew = fmaxf(mrun[i], pm);
      float factor = __expf(mrun[i] - mnew);
      mrun[i] = mnew;
      float ps = 0.f;
#pragma unroll
      for (int cb = 0; cb < 4; cb++) {
        p[cb][i] = __expf(s[cb][i] - mnew);
        ps += p[cb][i];
      }
#pragma unroll
      for (int msk = 1; msk < 16; msk <<= 1) ps += __shfl_xor(ps, msk);
      lrun[i] = lrun[i] * factor + ps;
#pragma unroll
      for (int nb = 0; nb < 4; nb++) o[nb][i] *= factor;
    }
    // P -> per-wave LDS (re-fragment for PV)
#pragma unroll
    for (int cb = 0; cb < 4; cb++)
#pragma unroll
      for (int i = 0; i < 4; i++)
        Plds[w][(l >> 4) * 4 + i][cb * 16 + (l & 15)] = (bf16)p[cb][i];
    // O += P V
#pragma unroll
    for (int kc = 0; kc < 2; kc++) {
      bf16x8 pa = *(const bf16x8*)&Plds[w][l & 15][kc * 32 + (l >> 4) * 8];
#pragma unroll
      for (int nb = 0; nb < 4; nb++) {
        int dr = nb * 16 + (l & 15);
        int c = kc * 4 + (l >> 4);
        bf16x8 vb = *(const bf16x8*)(VldsB + dr * 128 + ((c ^ (dr & 7)) * 16));
        o[nb] = __builtin_amdgcn_mfma_f32_16x16x32_bf16(pa, vb, o[nb], 0, 0, 0);
      }
    }
  }
  // epilogue
#pragma unroll
  for (int i = 0; i < 4; i++) {
    float inv = 1.f / lrun[i];
    int grow = b * Tc + q0 + w * 16 + (l >> 4) * 4 + i;
#pragma unroll
    for (int nb = 0; nb < 4; nb++) {
      int gcol = h * 64 + nb * 16 + (l & 15);
      O[(long)grow * Cc + gcol] = (bf16)(o[nb][i] * inv);
    }
  }
}

extern "C" void kernel_launch(void* const* d_in, const int* in_sizes, int n_in,
                              void* d_out, int out_size, void* d_ws,
                              size_t ws_size, hipStream_t stream) {
  const float* x = (const float*)d_in[0];
  const float* qkv_w = (const float*)d_in[1];
  const float* qkv_b = (const float*)d_in[2];
  const float* out_w = (const float*)d_in[3];
  const float* out_b = (const float*)d_in[4];
  float* out = (float*)d_out;
  char* ws = (char*)d_ws;
  // layout (MiB offsets): xb/Obuf share 0..16 (lifetimes disjoint)
  bf16* xb = (bf16*)(ws);                            // 16 MiB (x bf16)
  bf16* Obuf = (bf16*)(ws);                          // reuse after GEMM1
  bf16* wqkvT = (bf16*)(ws + (16ull << 20));         // 6 MiB
  bf16* woT = (bf16*)(ws + (22ull << 20));           // 2 MiB
  bf16* Ybuf = (bf16*)(ws + (24ull << 20));          // 48 MiB
  bf16* Vtb = (bf16*)(ws + (72ull << 20));           // 16 MiB  (total 88 MiB)

  cast_bf16_kernel<<<2048, 256, 0, stream>>>(x, xb, Mrows * Cc / 8);
  transpose_cast_kernel<<<dim3(N3 / 32, Cc / 32), dim3(32, 8), 0, stream>>>(
      qkv_w, wqkvT, Cc, N3);
  transpose_cast_kernel<<<dim3(Cc / 32, Cc / 32), dim3(32, 8), 0, stream>>>(
      out_w, woT, Cc, Cc);
  gemm_bt_kernel<bf16><<<dim3(Mrows / 128, N3 / 128), 256, 0, stream>>>(
      xb, wqkvT, qkv_b, Ybuf, Mrows, N3, Cc);
  transpose_v_kernel<<<dim3(Tc / 32, 2, Bc * Hc), dim3(32, 8), 0, stream>>>(
      Ybuf, Vtb);
  flash_kernel<<<dim3(Tc / 64, Bc * Hc), 256, 0, stream>>>(Ybuf, Vtb, Obuf);
  gemm_bt_kernel<float><<<dim3(Mrows / 128, Cc / 128), 256, 0, stream>>>(
      Obuf, woT, out_b, out, Mrows, Cc, Cc);
}